// Round 5
// baseline (175.727 us; speedup 1.0000x reference)
//
#include <hip/hip_runtime.h>

// Problem: H=W=384, F=K=256. M = 147456 rows.
// out[m,f] = sum_k d[m,k] * y[k,f],  y = x[stations] @ W  (256x256, tiny)
#define FF 256
#define KK 256
#define ITERS 12               // 16-row tiles per wave
#define NBLK 1536              // 1536 blk * 4 waves = 6144 waves
                               // = 8 col-slices * 768 row-groups; 768*12*16 = 147456

typedef __attribute__((ext_vector_type(8))) short bf16x8;   // 8 bf16 (4 VGPR)
typedef __attribute__((ext_vector_type(4))) float f32x4;    // MFMA C/D frag

// float -> bf16 bits, round-to-nearest-even
__device__ inline short f2bf(float x) {
    unsigned u = __float_as_uint(x);
    unsigned r = u + 0x7FFFu + ((u >> 16) & 1u);
    return (short)(r >> 16);
}

// Kernel 1: y[k][f] = sum_j x[sx[k],sy[k],j] * W[j][f], stored bf16 in
// FRAGMENT ORDER so kernel-2 B loads are lane-contiguous 16B/lane:
//   idx(k,f) = ((f>>4)*8 + (k>>5))*512 + (((k>>3)&3)*16 + (f&15))*8 + (k&7)
__global__ __launch_bounds__(256) void station_kernel(
        const float* __restrict__ x, const float* __restrict__ W,
        const int* __restrict__ sx, const int* __restrict__ sy,
        short* __restrict__ yp) {
    __shared__ float xrow[FF];
    const int k = blockIdx.x;
    const int f = threadIdx.x;
    const long base = ((long)sx[k] * 384 + (long)sy[k]) * FF;
    xrow[f] = x[base + f];
    __syncthreads();
    float acc = 0.f;
    #pragma unroll 8
    for (int j = 0; j < FF; ++j)
        acc += xrow[j] * W[j * FF + f];   // coalesced across f
    const int idx = ((f >> 4) * 8 + (k >> 5)) * 512
                  + (((k >> 3) & 3) * 16 + (f & 15)) * 8 + (k & 7);
    yp[idx] = f2bf(acc);
}

// Kernel 2: barrier-free, LDS-free. Each wave independent: owns a 32-col
// slice (B-fragments resident, 64 VGPR, loaded once), loops over 12
// sixteen-row tiles; A straight from global (16B/lane), C stored direct.
__global__ __launch_bounds__(256, 3) void gemm_kernel(
        const float* __restrict__ d, const short* __restrict__ yp,
        float* __restrict__ out) {
    const int t    = threadIdx.x;
    const int lane = t & 63;
    const int g    = blockIdx.x * 4 + (t >> 6);  // global wave id
    const int cs   = g & 7;                      // col slice: 32 cols
    const int rg   = g >> 3;                     // row group: 192 rows
    const int l15  = lane & 15;
    const int lg   = lane >> 4;

    // ---- B fragments: resident for the whole wave, 16 coalesced loads ----
    bf16x8 bfrag[8][2];
    #pragma unroll
    for (int kf = 0; kf < 8; ++kf)
        #pragma unroll
        for (int nf = 0; nf < 2; ++nf) {
            const int grp = cs * 2 + nf;
            bfrag[kf][nf] =
                *(const bf16x8*)(yp + ((grp * 8 + kf) << 9) + (lane << 3));
        }

    const long mbase = (long)rg * (16 * ITERS);

    for (int it = 0; it < ITERS; ++it) {
        const long m0 = mbase + (long)it * 16;
        // A: lane reads d[m0 + l15][kf*32 + lg*8 .. +7] (16 B, contiguous)
        const float* dp = d + (m0 + l15) * KK + lg * 8;

        float4 pv[16];
        #pragma unroll
        for (int kf = 0; kf < 8; ++kf) {
            pv[2 * kf]     = *(const float4*)(dp + kf * 32);
            pv[2 * kf + 1] = *(const float4*)(dp + kf * 32 + 4);
        }

        f32x4 acc[2];
        #pragma unroll
        for (int nf = 0; nf < 2; ++nf)
            #pragma unroll
            for (int q = 0; q < 4; ++q) acc[nf][q] = 0.f;

        #pragma unroll
        for (int kf = 0; kf < 8; ++kf) {
            const float4 lo = pv[2 * kf];
            const float4 hi = pv[2 * kf + 1];
            bf16x8 a;
            a[0] = f2bf(lo.x); a[1] = f2bf(lo.y);
            a[2] = f2bf(lo.z); a[3] = f2bf(lo.w);
            a[4] = f2bf(hi.x); a[5] = f2bf(hi.y);
            a[6] = f2bf(hi.z); a[7] = f2bf(hi.w);
            acc[0] = __builtin_amdgcn_mfma_f32_16x16x32_bf16(
                         a, bfrag[kf][0], acc[0], 0, 0, 0);
            acc[1] = __builtin_amdgcn_mfma_f32_16x16x32_bf16(
                         a, bfrag[kf][1], acc[1], 0, 0, 0);
        }

        // C store: row = lg*4 + q, col = cs*32 + nf*16 + l15
        float* ob = out + m0 * FF + cs * 32;
        #pragma unroll
        for (int nf = 0; nf < 2; ++nf)
            #pragma unroll
            for (int q = 0; q < 4; ++q)
                ob[(long)(lg * 4 + q) * FF + nf * 16 + l15] = acc[nf][q];
    }
}

extern "C" void kernel_launch(void* const* d_in, const int* in_sizes, int n_in,
                              void* d_out, int out_size, void* d_ws, size_t ws_size,
                              hipStream_t stream) {
    const float* x  = (const float*)d_in[0];
    const float* d  = (const float*)d_in[1];
    const float* W  = (const float*)d_in[2];
    const int*   sx = (const int*)d_in[3];
    const int*   sy = (const int*)d_in[4];
    float* out = (float*)d_out;
    short* yp  = (short*)d_ws;   // 256*256 bf16 = 128 KB packed fragment buffer

    station_kernel<<<dim3(KK), dim3(FF), 0, stream>>>(x, W, sx, sy, yp);
    gemm_kernel<<<dim3(NBLK), dim3(256), 0, stream>>>(d, yp, out);
}

// Round 6
// 81.109 us; speedup vs baseline: 2.1666x; 2.1666x over previous
//
#include <hip/hip_runtime.h>

// Problem: H=W=384, F=K=256. M = 147456 rows.
// out[m,f] = sum_k d[m,k] * y[k,f],  y = x[stations] @ W  (256x256, tiny)
#define FF 256
#define KK 256
#define RR 32                  // rows per stripe
#define STRIPES 9              // stripes per block
#define NBLK 512               // 512 * 9 * 32 = 147456 rows; 2 blocks/CU

typedef __attribute__((ext_vector_type(8))) short bf16x8;   // 8 bf16 (4 VGPR)
typedef __attribute__((ext_vector_type(4))) float f32x4;    // MFMA C/D frag
typedef __attribute__((ext_vector_type(4))) short short4v;  // 4 bf16 (8 B)

// float -> bf16 bits, round-to-nearest-even
__device__ inline short f2bf(float x) {
    unsigned u = __float_as_uint(x);
    unsigned r = u + 0x7FFFu + ((u >> 16) & 1u);
    return (short)(r >> 16);
}

// Kernel 1: y[k][f] = sum_j x[sx[k],sy[k],j] * W[j][f], stored bf16 in
// FRAGMENT ORDER so kernel-2 B loads are lane-contiguous 16B/lane:
//   idx(k,f) = ((f>>4)*8 + (k>>5))*512 + (((k>>3)&3)*16 + (f&15))*8 + (k&7)
__global__ __launch_bounds__(256) void station_kernel(
        const float* __restrict__ x, const float* __restrict__ W,
        const int* __restrict__ sx, const int* __restrict__ sy,
        short* __restrict__ yp) {
    __shared__ float xrow[FF];
    const int k = blockIdx.x;
    const int f = threadIdx.x;
    const long base = ((long)sx[k] * 384 + (long)sy[k]) * FF;
    xrow[f] = x[base + f];
    __syncthreads();
    float acc = 0.f;
    #pragma unroll 8
    for (int j = 0; j < FF; ++j)
        acc += xrow[j] * W[j * FF + f];   // coalesced across f
    const int idx = ((f >> 4) * 8 + (k >> 5)) * 512
                  + (((k >> 3) & 3) * 16 + (f & 15)) * 8 + (k & 7);
    yp[idx] = f2bf(acc);
}

// Kernel 2: 512-thread blocks (8 waves), wave owns a 32-col slice with its
// B-fragments FORCED resident via asm value-barrier (anti-rematerialization).
// 9 stripes/block, double-buffered bf16 LDS, T14 issue-early/convert-late.
__global__ __launch_bounds__(512, 4) void gemm_kernel(
        const float* __restrict__ d, const short* __restrict__ yp,
        float* __restrict__ out) {
    __shared__ __align__(16) short lds[2][RR * KK];   // 2 x 16 KB, swizzled
    const int t    = threadIdx.x;
    const int lane = t & 63;
    const int wid  = t >> 6;          // 0..7: 32-col slice
    const int l15  = lane & 15;
    const int lg   = lane >> 4;       // 0..3: k-subgroup
    const long mblk = (long)blockIdx.x * (RR * STRIPES);

    char* lb0 = (char*)lds[0];
    char* lb1 = (char*)lds[1];

    // ---- B fragments: 16 x 16B/lane coalesced loads, once per block ----
    bf16x8 bfrag[8][2];
    #pragma unroll
    for (int kf = 0; kf < 8; ++kf)
        #pragma unroll
        for (int nf = 0; nf < 2; ++nf) {
            const int g = wid * 2 + nf;
            bfrag[kf][nf] = *(const bf16x8*)(yp + ((g * 8 + kf) << 9) + (lane << 3));
        }
    // Anti-remat value barrier: compiler must keep these in registers; it can
    // no longer re-derive them from the (restrict, loop-invariant) loads.
    asm volatile("" :
        "+v"(bfrag[0][0]), "+v"(bfrag[0][1]), "+v"(bfrag[1][0]), "+v"(bfrag[1][1]),
        "+v"(bfrag[2][0]), "+v"(bfrag[2][1]), "+v"(bfrag[3][0]), "+v"(bfrag[3][1]),
        "+v"(bfrag[4][0]), "+v"(bfrag[4][1]), "+v"(bfrag[5][0]), "+v"(bfrag[5][1]),
        "+v"(bfrag[6][0]), "+v"(bfrag[6][1]), "+v"(bfrag[7][0]), "+v"(bfrag[7][1]));

    // staging geometry: pass p covers row p*8 + wid, lane writes 8B at col 8*(t&63)
    const int scol = (t & 63) * 8;

    // ---- prologue: load + stage stripe 0 into buf0 ----
    float4 pv[4];
    {
        const float* dp = d + mblk * KK;
        #pragma unroll
        for (int p = 0; p < 4; ++p)
            pv[p] = *(const float4*)(dp + (p * 512 + t) * 4);
        #pragma unroll
        for (int p = 0; p < 4; ++p) {
            const int row = p * 8 + wid;
            int byte = row * 512 + scol;
            byte ^= (row & 7) << 4;               // bank swizzle (G4)
            short4v b;
            b.x = f2bf(pv[p].x); b.y = f2bf(pv[p].y);
            b.z = f2bf(pv[p].z); b.w = f2bf(pv[p].w);
            *(short4v*)(lb0 + byte) = b;
        }
    }
    __syncthreads();

    for (int s = 0; s < STRIPES; ++s) {
        const long m0 = mblk + (long)s * RR;
        char* cur = (s & 1) ? lb1 : lb0;
        char* nxt = (s & 1) ? lb0 : lb1;

        // (1) issue next stripe's global loads — vmcnt waits land at convert
        if (s + 1 < STRIPES) {
            const float* dp = d + (m0 + RR) * KK;
            #pragma unroll
            for (int p = 0; p < 4; ++p)
                pv[p] = *(const float4*)(dp + (p * 512 + t) * 4);
        }

        // (2) compute current stripe: A from LDS, B from registers
        f32x4 acc[2][2];
        #pragma unroll
        for (int mt = 0; mt < 2; ++mt)
            #pragma unroll
            for (int nf = 0; nf < 2; ++nf)
                #pragma unroll
                for (int q = 0; q < 4; ++q) acc[mt][nf][q] = 0.f;

        #pragma unroll
        for (int kf = 0; kf < 8; ++kf) {
            const int cb = kf * 64 + lg * 16;
            const int xo = (l15 & 7) << 4;        // (16+l15)&7 == l15&7
            bf16x8 a0 = *(const bf16x8*)(cur + ((l15 * 512 + cb) ^ xo));
            bf16x8 a1 = *(const bf16x8*)(cur + (((16 + l15) * 512 + cb) ^ xo));
            #pragma unroll
            for (int nf = 0; nf < 2; ++nf) {
                acc[0][nf] = __builtin_amdgcn_mfma_f32_16x16x32_bf16(
                                 a0, bfrag[kf][nf], acc[0][nf], 0, 0, 0);
                acc[1][nf] = __builtin_amdgcn_mfma_f32_16x16x32_bf16(
                                 a1, bfrag[kf][nf], acc[1][nf], 0, 0, 0);
            }
        }

        // (3) store C: row = mt*16 + lg*4 + q, col = wid*32 + nf*16 + l15
        float* ob = out + m0 * FF + wid * 32;
        #pragma unroll
        for (int mt = 0; mt < 2; ++mt)
            #pragma unroll
            for (int nf = 0; nf < 2; ++nf)
                #pragma unroll
                for (int q = 0; q < 4; ++q)
                    ob[(long)(mt * 16 + lg * 4 + q) * FF + nf * 16 + l15]
                        = acc[mt][nf][q];

        // (4) convert + LDS-write pending stripe into nxt
        if (s + 1 < STRIPES) {
            #pragma unroll
            for (int p = 0; p < 4; ++p) {
                const int row = p * 8 + wid;
                int byte = row * 512 + scol;
                byte ^= (row & 7) << 4;
                short4v b;
                b.x = f2bf(pv[p].x); b.y = f2bf(pv[p].y);
                b.z = f2bf(pv[p].z); b.w = f2bf(pv[p].w);
                *(short4v*)(nxt + byte) = b;
            }
        }

        // (5) one barrier per stripe
        __syncthreads();
    }
}

extern "C" void kernel_launch(void* const* d_in, const int* in_sizes, int n_in,
                              void* d_out, int out_size, void* d_ws, size_t ws_size,
                              hipStream_t stream) {
    const float* x  = (const float*)d_in[0];
    const float* d  = (const float*)d_in[1];
    const float* W  = (const float*)d_in[2];
    const int*   sx = (const int*)d_in[3];
    const int*   sy = (const int*)d_in[4];
    float* out = (float*)d_out;
    short* yp  = (short*)d_ws;   // 256*256 bf16 = 128 KB packed fragment buffer

    station_kernel<<<dim3(KK), dim3(FF), 0, stream>>>(x, W, sx, sy, yp);
    gemm_kernel<<<dim3(NBLK), dim3(512), 0, stream>>>(d, yp, out);
}